// Round 2
// baseline (5164.804 us; speedup 1.0000x reference)
//
#include <hip/hip_runtime.h>
#include <hip/hip_bf16.h>

typedef __bf16 bf16x8 __attribute__((ext_vector_type(8)));
typedef __bf16 bf16x4 __attribute__((ext_vector_type(4)));
typedef float f32x4 __attribute__((ext_vector_type(4)));
using bf16 = __hip_bfloat16;

// ---------------------------------------------------------------------------
// MFMA GEMM: C[M,Nout] = A[M,K] @ W[K,Nout] (+bias)(+epilogue)
// BM=64, BN=128, BK=128. 256 threads = 4 waves; wave w owns rows w*16..+15.
// A is bf16 (AF32=false) or f32 converted on stage (AF32=true). W is f32,
// converted to bf16 during LDS staging. Accumulate f32.
// MODE 0: store bf16. MODE 1: store f32. MODE 2: silu->bf16. MODE 3: +resid, f32.
// ---------------------------------------------------------------------------
template <int MODE, bool AF32>
__global__ __launch_bounds__(256) void gemm_bias_k(
    const void* __restrict__ Av, const float* __restrict__ W,
    const float* __restrict__ bias, void* __restrict__ Cout,
    const float* __restrict__ resid, int M, int K, int Nout)
{
    __shared__ __bf16 As[64][136];    // row-major A tile (pad stride 136 -> 272 B)
    __shared__ __bf16 Ws[128][136];   // transposed W tile: Ws[n][k]

    const int tid  = threadIdx.x;
    const int wave = tid >> 6;
    const int lane = tid & 63;
    const int row0 = blockIdx.x * 64;
    const int col0 = blockIdx.y * 128;

    f32x4 acc[8];
#pragma unroll
    for (int i = 0; i < 8; i++) acc[i] = (f32x4){0.f, 0.f, 0.f, 0.f};

    for (int k0 = 0; k0 < K; k0 += 128) {
        // ---- stage A tile (64 x 128) ----
        if constexpr (AF32) {
            const float* A = (const float*)Av;
#pragma unroll
            for (int i = 0; i < 8; i++) {          // 2048 float4 chunks
                int idx = tid + i * 256;
                int r = idx >> 5, c4 = idx & 31;
                bf16x4 o;
                if (row0 + r < M) {
                    f32x4 v = *reinterpret_cast<const f32x4*>(A + (size_t)(row0 + r) * K + k0 + c4 * 4);
#pragma unroll
                    for (int j = 0; j < 4; j++) o[j] = (__bf16)v[j];
                } else {
#pragma unroll
                    for (int j = 0; j < 4; j++) o[j] = (__bf16)0.f;
                }
                *reinterpret_cast<bf16x4*>(&As[r][c4 * 4]) = o;
            }
        } else {
            const bf16* A = (const bf16*)Av;
#pragma unroll
            for (int i = 0; i < 4; i++) {          // 1024 bf16x8 chunks
                int idx = tid + i * 256;
                int r = idx >> 4, c8 = idx & 15;
                bf16x8 v;
                if (row0 + r < M) {
                    v = *reinterpret_cast<const bf16x8*>(A + (size_t)(row0 + r) * K + k0 + c8 * 8);
                } else {
#pragma unroll
                    for (int j = 0; j < 8; j++) v[j] = (__bf16)0.f;
                }
                *reinterpret_cast<bf16x8*>(&As[r][c8 * 8]) = v;
            }
        }
        // ---- stage W tile (128 x 128), f32 -> bf16, transposed scatter ----
#pragma unroll
        for (int i = 0; i < 16; i++) {             // 4096 float4 chunks
            int idx = tid + i * 256;
            int kk = idx >> 5, n4 = idx & 31;
            f32x4 v = *reinterpret_cast<const f32x4*>(W + (size_t)(k0 + kk) * Nout + col0 + n4 * 4);
#pragma unroll
            for (int j = 0; j < 4; j++) Ws[n4 * 4 + j][kk] = (__bf16)v[j];
        }
        __syncthreads();

        const int mrow = wave * 16 + (lane & 15);
        const int koff = (lane >> 4) * 8;
#pragma unroll
        for (int kk = 0; kk < 128; kk += 32) {
            bf16x8 a = *reinterpret_cast<const bf16x8*>(&As[mrow][kk + koff]);
#pragma unroll
            for (int ct = 0; ct < 8; ct++) {
                bf16x8 b = *reinterpret_cast<const bf16x8*>(&Ws[ct * 16 + (lane & 15)][kk + koff]);
                acc[ct] = __builtin_amdgcn_mfma_f32_16x16x32_bf16(a, b, acc[ct], 0, 0, 0);
            }
        }
        __syncthreads();
    }

    // epilogue: C/D layout col=lane&15, row=(lane>>4)*4+reg
    const int rbase = row0 + wave * 16 + ((lane >> 4) << 2);
#pragma unroll
    for (int ct = 0; ct < 8; ct++) {
        int col = col0 + ct * 16 + (lane & 15);
        float bv = bias ? bias[col] : 0.f;
#pragma unroll
        for (int r = 0; r < 4; r++) {
            int row = rbase + r;
            if (row >= M) continue;
            float v = acc[ct][r] + bv;
            if constexpr (MODE == 2) v = v / (1.f + __expf(-v));          // silu
            if constexpr (MODE == 3) v += resid[(size_t)row * 128 + col]; // + xn residual
            if constexpr (MODE == 1 || MODE == 3) {
                ((float*)Cout)[(size_t)row * Nout + col] = v;
            } else {
                ((bf16*)Cout)[(size_t)row * Nout + col] = __float2bfloat16(v);
            }
        }
    }
}

// ---------------------------------------------------------------------------
// LayerNorm: one wave per row (D=128, 2 channels/lane). f32 in -> bf16 out.
// ---------------------------------------------------------------------------
__global__ __launch_bounds__(256) void ln_k(
    const float* __restrict__ x, const float* __restrict__ g,
    const float* __restrict__ beta, bf16* __restrict__ h, int Nrows)
{
    int row = blockIdx.x * 4 + (threadIdx.x >> 6);
    int lane = threadIdx.x & 63;
    if (row >= Nrows) return;
    size_t base = (size_t)row * 128;
    float v0 = x[base + lane], v1 = x[base + lane + 64];
    float s = v0 + v1, ss = v0 * v0 + v1 * v1;
#pragma unroll
    for (int off = 32; off; off >>= 1) {
        s += __shfl_xor(s, off, 64);
        ss += __shfl_xor(ss, off, 64);
    }
    float mu = s * (1.f / 128.f);
    float var = ss * (1.f / 128.f) - mu * mu;
    float rs = rsqrtf(var + 1e-5f);
    h[base + lane]      = __float2bfloat16((v0 - mu) * rs * g[lane] + beta[lane]);
    h[base + lane + 64] = __float2bfloat16((v1 - mu) * rs * g[lane + 64] + beta[lane + 64]);
}

// ---------------------------------------------------------------------------
// Edge pass: 4 threads/edge, 32 channels (=2 heads) each.
// p = exp(q.k/4) (logits tiny: no max-subtraction needed; normalization is
// invariant). f32 atomics into out_acc and z.
// ---------------------------------------------------------------------------
__global__ __launch_bounds__(256) void edge_k(
    const int* __restrict__ ei, const bf16* __restrict__ Ep,
    const bf16* __restrict__ Q, const bf16* __restrict__ Kt,
    const bf16* __restrict__ Vt, float* __restrict__ out_acc,
    float* __restrict__ z, int E)
{
    int gid = blockIdx.x * 256 + threadIdx.x;
    int e = gid >> 2;
    if (e >= E) return;
    int part = gid & 3;
    int c0 = part * 32;
    int src = ei[e];
    int dst = ei[E + e];
    const bf16* ep = Ep + (size_t)e * 128 + c0;
    const bf16* qp = Q + (size_t)dst * 128 + c0;
    const bf16* kp = Kt + (size_t)src * 128 + c0;
    const bf16* vp = Vt + (size_t)src * 128 + c0;
    float* oa = out_acc + (size_t)dst * 128 + c0;

#pragma unroll
    for (int hh = 0; hh < 2; hh++) {
        bf16x8 e0 = *reinterpret_cast<const bf16x8*>(ep + hh * 16);
        bf16x8 e1 = *reinterpret_cast<const bf16x8*>(ep + hh * 16 + 8);
        bf16x8 q0 = *reinterpret_cast<const bf16x8*>(qp + hh * 16);
        bf16x8 q1 = *reinterpret_cast<const bf16x8*>(qp + hh * 16 + 8);
        bf16x8 k0 = *reinterpret_cast<const bf16x8*>(kp + hh * 16);
        bf16x8 k1 = *reinterpret_cast<const bf16x8*>(kp + hh * 16 + 8);
        float lg = 0.f;
#pragma unroll
        for (int j = 0; j < 8; j++) lg += (float)q0[j] * ((float)k0[j] + (float)e0[j]);
#pragma unroll
        for (int j = 0; j < 8; j++) lg += (float)q1[j] * ((float)k1[j] + (float)e1[j]);
        float p = __expf(lg * 0.25f);
        atomicAdd(&z[(size_t)dst * 8 + part * 2 + hh], p);
        bf16x8 v0 = *reinterpret_cast<const bf16x8*>(vp + hh * 16);
        bf16x8 v1 = *reinterpret_cast<const bf16x8*>(vp + hh * 16 + 8);
#pragma unroll
        for (int j = 0; j < 8; j++) atomicAdd(oa + hh * 16 + j, p * ((float)v0[j] + (float)e0[j]));
#pragma unroll
        for (int j = 0; j < 8; j++) atomicAdd(oa + hh * 16 + 8 + j, p * ((float)v1[j] + (float)e1[j]));
    }
}

// ---------------------------------------------------------------------------
// Post: normalize by z, +skip, xn = x + alpha*out (f32), LN2 -> h2 (bf16)
// ---------------------------------------------------------------------------
__global__ __launch_bounds__(256) void post_k(
    const float* __restrict__ x, const float* __restrict__ out_acc,
    const float* __restrict__ z, const float* __restrict__ S,
    const float* __restrict__ alpha, const float* __restrict__ g,
    const float* __restrict__ beta, float* __restrict__ xn,
    bf16* __restrict__ h2, int Nrows)
{
    int row = blockIdx.x * 4 + (threadIdx.x >> 6);
    int lane = threadIdx.x & 63;
    if (row >= Nrows) return;
    float al = alpha[0];
    size_t base = (size_t)row * 128;
    int c0 = lane, c1 = lane + 64;
    float o0 = out_acc[base + c0] / (z[(size_t)row * 8 + (c0 >> 4)] + 1e-16f) + S[base + c0];
    float o1 = out_acc[base + c1] / (z[(size_t)row * 8 + (c1 >> 4)] + 1e-16f) + S[base + c1];
    float x0 = x[base + c0] + al * o0;
    float x1 = x[base + c1] + al * o1;
    xn[base + c0] = x0;
    xn[base + c1] = x1;
    float s = x0 + x1, ss = x0 * x0 + x1 * x1;
#pragma unroll
    for (int off = 32; off; off >>= 1) {
        s += __shfl_xor(s, off, 64);
        ss += __shfl_xor(ss, off, 64);
    }
    float mu = s * (1.f / 128.f);
    float var = ss * (1.f / 128.f) - mu * mu;
    float rs = rsqrtf(var + 1e-5f);
    h2[base + c0] = __float2bfloat16((x0 - mu) * rs * g[c0] + beta[c0]);
    h2[base + c1] = __float2bfloat16((x1 - mu) * rs * g[c1] + beta[c1]);
}

// ---------------------------------------------------------------------------
extern "C" void kernel_launch(void* const* d_in, const int* in_sizes, int n_in,
                              void* d_out, int out_size, void* d_ws, size_t ws_size,
                              hipStream_t stream)
{
    const float* x         = (const float*)d_in[0];
    const float* edge_attr = (const float*)d_in[1];
    const int*   ei        = (const int*)d_in[2];
    const float* Wq = (const float*)d_in[3];  const float* bq = (const float*)d_in[4];
    const float* Wk = (const float*)d_in[5];  const float* bk = (const float*)d_in[6];
    const float* Wv = (const float*)d_in[7];  const float* bv = (const float*)d_in[8];
    const float* We = (const float*)d_in[9];
    const float* Wskip = (const float*)d_in[10]; const float* bskip = (const float*)d_in[11];
    const float* W1 = (const float*)d_in[12]; const float* b1 = (const float*)d_in[13];
    const float* W2 = (const float*)d_in[14]; const float* b2 = (const float*)d_in[15];
    const float* g1 = (const float*)d_in[16]; const float* beta1 = (const float*)d_in[17];
    const float* g2 = (const float*)d_in[18]; const float* beta2 = (const float*)d_in[19];
    const float* alpha = (const float*)d_in[20];

    const int N = in_sizes[0] / 128;
    const int E = in_sizes[2] / 2;

    char* w = (char*)d_ws;
    auto alloc = [&](size_t bytes) {
        char* p = w;
        w += (bytes + 255) & ~(size_t)255;
        return p;
    };
    bf16*  h       = (bf16*)alloc((size_t)N * 128 * 2);
    bf16*  Qb      = (bf16*)alloc((size_t)N * 128 * 2);
    bf16*  Kb      = (bf16*)alloc((size_t)N * 128 * 2);
    bf16*  Vb      = (bf16*)alloc((size_t)N * 128 * 2);
    float* Sb      = (float*)alloc((size_t)N * 128 * 4);
    bf16*  Ep      = (bf16*)alloc((size_t)E * 128 * 2);
    float* out_acc = (float*)alloc((size_t)N * 128 * 4);   // contiguous with z
    float* zbuf    = (float*)alloc((size_t)N * 8 * 4);
    float* xn      = (float*)alloc((size_t)N * 128 * 4);
    bf16*  h2      = (bf16*)alloc((size_t)N * 128 * 2);
    bf16*  t       = (bf16*)alloc((size_t)N * 512 * 2);

    // 1. LN1
    ln_k<<<(N + 3) / 4, 256, 0, stream>>>(x, g1, beta1, h, N);

    // 2. node GEMMs: Q, K, V (bf16 out), Skip (f32 out)
    dim3 gN((N + 63) / 64, 1);
    gemm_bias_k<0, false><<<gN, 256, 0, stream>>>(h, Wq, bq, Qb, nullptr, N, 128, 128);
    gemm_bias_k<0, false><<<gN, 256, 0, stream>>>(h, Wk, bk, Kb, nullptr, N, 128, 128);
    gemm_bias_k<0, false><<<gN, 256, 0, stream>>>(h, Wv, bv, Vb, nullptr, N, 128, 128);
    gemm_bias_k<1, false><<<gN, 256, 0, stream>>>(h, Wskip, bskip, Sb, nullptr, N, 128, 128);

    // 3. edge projection: Ep = edge_attr(f32) @ We -> bf16
    dim3 gE((E + 63) / 64, 1);
    gemm_bias_k<0, true><<<gE, 256, 0, stream>>>(edge_attr, We, nullptr, Ep, nullptr, E, 128, 128);

    // 4. zero accumulators (out_acc + z contiguous)
    hipMemsetAsync(out_acc, 0, (size_t)N * 128 * 4 + (size_t)N * 8 * 4, stream);

    // 5. edge pass
    edge_k<<<(E * 4 + 255) / 256, 256, 0, stream>>>(ei, Ep, Qb, Kb, Vb, out_acc, zbuf, E);

    // 6. normalize + skip + residual + LN2
    post_k<<<(N + 3) / 4, 256, 0, stream>>>(x, out_acc, zbuf, Sb, alpha, g2, beta2, xn, h2, N);

    // 7. FFN
    gemm_bias_k<2, false><<<dim3((N + 63) / 64, 4), 256, 0, stream>>>(h2, W1, b1, t, nullptr, N, 128, 512);
    gemm_bias_k<3, false><<<dim3((N + 63) / 64, 1), 256, 0, stream>>>(t, W2, b2, d_out, xn, N, 512, 128);
}

// Round 3
// 1251.154 us; speedup vs baseline: 4.1280x; 4.1280x over previous
//
#include <hip/hip_runtime.h>
#include <hip/hip_bf16.h>

typedef __bf16 bf16x8 __attribute__((ext_vector_type(8)));
typedef __bf16 bf16x4 __attribute__((ext_vector_type(4)));
typedef __bf16 bf16x2 __attribute__((ext_vector_type(2)));
typedef float f32x4 __attribute__((ext_vector_type(4)));
using bf16 = __hip_bfloat16;

// ---------------------------------------------------------------------------
// MFMA GEMM: C[M,Nout] = A[M,K] @ W[K,Nout] (+bias)(+epilogue)
// BM=64, BN=128, BK=128. 256 threads = 4 waves; wave w owns rows w*16..+15.
// MODE 0: store bf16. MODE 1: store f32. MODE 2: silu->bf16. MODE 3: +resid, f32.
// ---------------------------------------------------------------------------
template <int MODE, bool AF32>
__global__ __launch_bounds__(256) void gemm_bias_k(
    const void* __restrict__ Av, const float* __restrict__ W,
    const float* __restrict__ bias, void* __restrict__ Cout,
    const float* __restrict__ resid, int M, int K, int Nout)
{
    __shared__ __bf16 As[64][136];
    __shared__ __bf16 Ws[128][136];   // transposed W tile: Ws[n][k]

    const int tid  = threadIdx.x;
    const int wave = tid >> 6;
    const int lane = tid & 63;
    const int row0 = blockIdx.x * 64;
    const int col0 = blockIdx.y * 128;

    f32x4 acc[8];
#pragma unroll
    for (int i = 0; i < 8; i++) acc[i] = (f32x4){0.f, 0.f, 0.f, 0.f};

    for (int k0 = 0; k0 < K; k0 += 128) {
        if constexpr (AF32) {
            const float* A = (const float*)Av;
#pragma unroll
            for (int i = 0; i < 8; i++) {
                int idx = tid + i * 256;
                int r = idx >> 5, c4 = idx & 31;
                bf16x4 o;
                if (row0 + r < M) {
                    f32x4 v = *reinterpret_cast<const f32x4*>(A + (size_t)(row0 + r) * K + k0 + c4 * 4);
#pragma unroll
                    for (int j = 0; j < 4; j++) o[j] = (__bf16)v[j];
                } else {
#pragma unroll
                    for (int j = 0; j < 4; j++) o[j] = (__bf16)0.f;
                }
                *reinterpret_cast<bf16x4*>(&As[r][c4 * 4]) = o;
            }
        } else {
            const bf16* A = (const bf16*)Av;
#pragma unroll
            for (int i = 0; i < 4; i++) {
                int idx = tid + i * 256;
                int r = idx >> 4, c8 = idx & 15;
                bf16x8 v;
                if (row0 + r < M) {
                    v = *reinterpret_cast<const bf16x8*>(A + (size_t)(row0 + r) * K + k0 + c8 * 8);
                } else {
#pragma unroll
                    for (int j = 0; j < 8; j++) v[j] = (__bf16)0.f;
                }
                *reinterpret_cast<bf16x8*>(&As[r][c8 * 8]) = v;
            }
        }
#pragma unroll
        for (int i = 0; i < 16; i++) {
            int idx = tid + i * 256;
            int kk = idx >> 5, n4 = idx & 31;
            f32x4 v = *reinterpret_cast<const f32x4*>(W + (size_t)(k0 + kk) * Nout + col0 + n4 * 4);
#pragma unroll
            for (int j = 0; j < 4; j++) Ws[n4 * 4 + j][kk] = (__bf16)v[j];
        }
        __syncthreads();

        const int mrow = wave * 16 + (lane & 15);
        const int koff = (lane >> 4) * 8;
#pragma unroll
        for (int kk = 0; kk < 128; kk += 32) {
            bf16x8 a = *reinterpret_cast<const bf16x8*>(&As[mrow][kk + koff]);
#pragma unroll
            for (int ct = 0; ct < 8; ct++) {
                bf16x8 b = *reinterpret_cast<const bf16x8*>(&Ws[ct * 16 + (lane & 15)][kk + koff]);
                acc[ct] = __builtin_amdgcn_mfma_f32_16x16x32_bf16(a, b, acc[ct], 0, 0, 0);
            }
        }
        __syncthreads();
    }

    const int rbase = row0 + wave * 16 + ((lane >> 4) << 2);
#pragma unroll
    for (int ct = 0; ct < 8; ct++) {
        int col = col0 + ct * 16 + (lane & 15);
        float bv = bias ? bias[col] : 0.f;
#pragma unroll
        for (int r = 0; r < 4; r++) {
            int row = rbase + r;
            if (row >= M) continue;
            float v = acc[ct][r] + bv;
            if constexpr (MODE == 2) v = v / (1.f + __expf(-v));
            if constexpr (MODE == 3) v += resid[(size_t)row * 128 + col];
            if constexpr (MODE == 1 || MODE == 3) {
                ((float*)Cout)[(size_t)row * Nout + col] = v;
            } else {
                ((bf16*)Cout)[(size_t)row * Nout + col] = __float2bfloat16(v);
            }
        }
    }
}

// ---------------------------------------------------------------------------
// LayerNorm: one wave per row (D=128, 2 channels/lane). f32 in -> bf16 out.
// ---------------------------------------------------------------------------
__global__ __launch_bounds__(256) void ln_k(
    const float* __restrict__ x, const float* __restrict__ g,
    const float* __restrict__ beta, bf16* __restrict__ h, int Nrows)
{
    int row = blockIdx.x * 4 + (threadIdx.x >> 6);
    int lane = threadIdx.x & 63;
    if (row >= Nrows) return;
    size_t base = (size_t)row * 128;
    float v0 = x[base + lane], v1 = x[base + lane + 64];
    float s = v0 + v1, ss = v0 * v0 + v1 * v1;
#pragma unroll
    for (int off = 32; off; off >>= 1) {
        s += __shfl_xor(s, off, 64);
        ss += __shfl_xor(ss, off, 64);
    }
    float mu = s * (1.f / 128.f);
    float var = ss * (1.f / 128.f) - mu * mu;
    float rs = rsqrtf(var + 1e-5f);
    h[base + lane]      = __float2bfloat16((v0 - mu) * rs * g[lane] + beta[lane]);
    h[base + lane + 64] = __float2bfloat16((v1 - mu) * rs * g[lane + 64] + beta[lane + 64]);
}

// ---------------------------------------------------------------------------
// CSR build: histogram of dst, exclusive scan, scatter (src,eid) pairs
// ---------------------------------------------------------------------------
__global__ __launch_bounds__(256) void hist_k(const int* __restrict__ ei, int* __restrict__ cnt, int E)
{
    int e = blockIdx.x * 256 + threadIdx.x;
    if (e < E) atomicAdd(&cnt[ei[E + e]], 1);
}

__global__ __launch_bounds__(1024) void scan_k(const int* __restrict__ cnt, int* __restrict__ offset, int N)
{
    __shared__ int tmp[1024];
    __shared__ int s_running;
    int tid = threadIdx.x;
    if (tid == 0) { s_running = 0; offset[0] = 0; }
    __syncthreads();
    for (int base = 0; base < N; base += 1024) {
        int v = (base + tid < N) ? cnt[base + tid] : 0;
        tmp[tid] = v;
        __syncthreads();
#pragma unroll
        for (int off = 1; off < 1024; off <<= 1) {
            int t = (tid >= off) ? tmp[tid - off] : 0;
            __syncthreads();
            tmp[tid] += t;
            __syncthreads();
        }
        int run = s_running;
        if (base + tid < N) offset[base + tid + 1] = run + tmp[tid];
        __syncthreads();
        if (tid == 0) s_running = run + tmp[1023];
        __syncthreads();
    }
}

__global__ __launch_bounds__(256) void scatter_k(
    const int* __restrict__ ei, const int* __restrict__ offset,
    int* __restrict__ cursor, int2* __restrict__ sorted, int E)
{
    int e = blockIdx.x * 256 + threadIdx.x;
    if (e >= E) return;
    int src = ei[e];
    int dst = ei[E + e];
    int r = atomicAdd(&cursor[dst], 1);
    sorted[offset[dst] + r] = make_int2(src, e);
}

// ---------------------------------------------------------------------------
// Fused gather: one wave per dst node. Walk incoming edges (CSR), compute
// p = exp(q.(k+e)/4), accumulate num = sum p*(v+e) and den = sum p in regs.
// Then normalize, +skip, residual (xn), LN2 -> h2. No feature atomics.
// Lane l holds channels 2l, 2l+1; head = l>>3 (8 lanes per 16-ch head).
// ---------------------------------------------------------------------------
__global__ __launch_bounds__(256) void gather_k(
    const int2* __restrict__ sorted, const int* __restrict__ offset,
    const bf16* __restrict__ Q, const bf16* __restrict__ Kt,
    const bf16* __restrict__ Vt, const bf16* __restrict__ Ep,
    const float* __restrict__ S, const float* __restrict__ x,
    const float* __restrict__ alpha, const float* __restrict__ g,
    const float* __restrict__ beta, float* __restrict__ xn,
    bf16* __restrict__ h2, int N)
{
    int node = blockIdx.x * 4 + (threadIdx.x >> 6);
    if (node >= N) return;
    int lane = threadIdx.x & 63;
    size_t base = (size_t)node * 128;
    int c = lane * 2;

    bf16x2 qv = *reinterpret_cast<const bf16x2*>(Q + base + c);
    float q0 = (float)qv[0], q1 = (float)qv[1];

    int start = offset[node], end = offset[node + 1];
    float den = 0.f, num0 = 0.f, num1 = 0.f;

    int2 se = (start < end) ? sorted[start] : make_int2(0, 0);
    for (int j = start; j < end; j++) {
        int2 cur = se;
        if (j + 1 < end) se = sorted[j + 1];
        size_t sb = (size_t)cur.x * 128 + c;
        size_t eb = (size_t)cur.y * 128 + c;
        bf16x2 kv = *reinterpret_cast<const bf16x2*>(Kt + sb);
        bf16x2 ev = *reinterpret_cast<const bf16x2*>(Ep + eb);
        bf16x2 vv = *reinterpret_cast<const bf16x2*>(Vt + sb);
        float e0 = (float)ev[0], e1 = (float)ev[1];
        float part = q0 * ((float)kv[0] + e0) + q1 * ((float)kv[1] + e1);
        part += __shfl_xor(part, 1, 64);
        part += __shfl_xor(part, 2, 64);
        part += __shfl_xor(part, 4, 64);   // reduced over the 8 lanes of this head
        float p = __expf(part * 0.25f);
        den  += p;
        num0 += p * ((float)vv[0] + e0);
        num1 += p * ((float)vv[1] + e1);
    }

    float invz = 1.f / (den + 1e-16f);
    float al = alpha[0];
    float o0 = num0 * invz + S[base + c];
    float o1 = num1 * invz + S[base + c + 1];
    float x0 = x[base + c] + al * o0;
    float x1 = x[base + c + 1] + al * o1;
    xn[base + c] = x0;
    xn[base + c + 1] = x1;

    float s = x0 + x1, ss = x0 * x0 + x1 * x1;
#pragma unroll
    for (int off = 32; off; off >>= 1) {
        s += __shfl_xor(s, off, 64);
        ss += __shfl_xor(ss, off, 64);
    }
    float mu = s * (1.f / 128.f);
    float var = ss * (1.f / 128.f) - mu * mu;
    float rs = rsqrtf(var + 1e-5f);
    h2[base + c]     = __float2bfloat16((x0 - mu) * rs * g[c] + beta[c]);
    h2[base + c + 1] = __float2bfloat16((x1 - mu) * rs * g[c + 1] + beta[c + 1]);
}

// ---------------------------------------------------------------------------
extern "C" void kernel_launch(void* const* d_in, const int* in_sizes, int n_in,
                              void* d_out, int out_size, void* d_ws, size_t ws_size,
                              hipStream_t stream)
{
    const float* x         = (const float*)d_in[0];
    const float* edge_attr = (const float*)d_in[1];
    const int*   ei        = (const int*)d_in[2];
    const float* Wq = (const float*)d_in[3];  const float* bq = (const float*)d_in[4];
    const float* Wk = (const float*)d_in[5];  const float* bk = (const float*)d_in[6];
    const float* Wv = (const float*)d_in[7];  const float* bv = (const float*)d_in[8];
    const float* We = (const float*)d_in[9];
    const float* Wskip = (const float*)d_in[10]; const float* bskip = (const float*)d_in[11];
    const float* W1 = (const float*)d_in[12]; const float* b1 = (const float*)d_in[13];
    const float* W2 = (const float*)d_in[14]; const float* b2 = (const float*)d_in[15];
    const float* g1 = (const float*)d_in[16]; const float* beta1 = (const float*)d_in[17];
    const float* g2 = (const float*)d_in[18]; const float* beta2 = (const float*)d_in[19];
    const float* alpha = (const float*)d_in[20];

    const int N = in_sizes[0] / 128;
    const int E = in_sizes[2] / 2;

    char* w = (char*)d_ws;
    auto alloc = [&](size_t bytes) {
        char* p = w;
        w += (bytes + 255) & ~(size_t)255;
        return p;
    };
    bf16*  h      = (bf16*)alloc((size_t)N * 128 * 2);
    bf16*  Qb     = (bf16*)alloc((size_t)N * 128 * 2);
    bf16*  Kb     = (bf16*)alloc((size_t)N * 128 * 2);
    bf16*  Vb     = (bf16*)alloc((size_t)N * 128 * 2);
    float* Sb     = (float*)alloc((size_t)N * 128 * 4);
    bf16*  Ep     = (bf16*)alloc((size_t)E * 128 * 2);
    float* xn     = (float*)alloc((size_t)N * 128 * 4);
    bf16*  h2     = (bf16*)alloc((size_t)N * 128 * 2);
    bf16*  t      = (bf16*)alloc((size_t)N * 512 * 2);
    int*   cnt    = (int*)alloc((size_t)N * 4);
    int*   cursor = (int*)alloc((size_t)N * 4);
    int*   offset = (int*)alloc((size_t)(N + 1) * 4);
    int2*  sorted = (int2*)alloc((size_t)E * 8);

    // CSR build (independent of GEMMs)
    hipMemsetAsync(cnt, 0, (size_t)N * 4, stream);
    hipMemsetAsync(cursor, 0, (size_t)N * 4, stream);
    hist_k<<<(E + 255) / 256, 256, 0, stream>>>(ei, cnt, E);
    scan_k<<<1, 1024, 0, stream>>>(cnt, offset, N);
    scatter_k<<<(E + 255) / 256, 256, 0, stream>>>(ei, offset, cursor, sorted, E);

    // LN1
    ln_k<<<(N + 3) / 4, 256, 0, stream>>>(x, g1, beta1, h, N);

    // node GEMMs: Q, K, V (bf16 out), Skip (f32 out)
    dim3 gN((N + 63) / 64, 1);
    gemm_bias_k<0, false><<<gN, 256, 0, stream>>>(h, Wq, bq, Qb, nullptr, N, 128, 128);
    gemm_bias_k<0, false><<<gN, 256, 0, stream>>>(h, Wk, bk, Kb, nullptr, N, 128, 128);
    gemm_bias_k<0, false><<<gN, 256, 0, stream>>>(h, Wv, bv, Vb, nullptr, N, 128, 128);
    gemm_bias_k<1, false><<<gN, 256, 0, stream>>>(h, Wskip, bskip, Sb, nullptr, N, 128, 128);

    // edge projection: Ep = edge_attr(f32) @ We -> bf16
    dim3 gE((E + 63) / 64, 1);
    gemm_bias_k<0, true><<<gE, 256, 0, stream>>>(edge_attr, We, nullptr, Ep, nullptr, E, 128, 128);

    // fused gather: attention + normalize + skip + residual + LN2
    gather_k<<<(N + 3) / 4, 256, 0, stream>>>(sorted, offset, Qb, Kb, Vb, Ep,
                                              Sb, x, alpha, g2, beta2, xn, h2, N);

    // FFN
    gemm_bias_k<2, false><<<dim3((N + 63) / 64, 4), 256, 0, stream>>>(h2, W1, b1, t, nullptr, N, 128, 512);
    gemm_bias_k<3, false><<<dim3((N + 63) / 64, 1), 256, 0, stream>>>(t, W2, b2, d_out, xn, N, 512, 128);
}

// Round 4
// 912.224 us; speedup vs baseline: 5.6618x; 1.3715x over previous
//
#include <hip/hip_runtime.h>
#include <hip/hip_bf16.h>

typedef __bf16 bf16x8 __attribute__((ext_vector_type(8)));
typedef __bf16 bf16x4 __attribute__((ext_vector_type(4)));
typedef __bf16 bf16x2 __attribute__((ext_vector_type(2)));
typedef float f32x4 __attribute__((ext_vector_type(4)));
using bf16 = __hip_bfloat16;

// ---------------------------------------------------------------------------
// Weight prep: WT[n*K + k] = (bf16) W[k*N + n]   (transpose + f32->bf16)
// ---------------------------------------------------------------------------
__global__ __launch_bounds__(256) void t_k(const float* __restrict__ W,
                                           bf16* __restrict__ WT, int K, int N)
{
    int idx = blockIdx.x * 256 + threadIdx.x;
    if (idx >= K * N) return;
    int n = idx / K, k = idx % K;
    WT[idx] = __float2bfloat16(W[(size_t)k * N + n]);
}

__global__ __launch_bounds__(256) void bcat_k(const float* __restrict__ a, const float* __restrict__ b,
                                              const float* __restrict__ c, const float* __restrict__ d,
                                              float* __restrict__ o)
{
    int i = threadIdx.x + blockIdx.x * 256;
    if (i >= 512) return;
    o[i] = (i < 128) ? a[i] : (i < 256) ? b[i - 128] : (i < 384) ? c[i - 256] : d[i - 384];
}

// ---------------------------------------------------------------------------
// MFMA GEMM: C[M,Nout] = A[M,K] @ WT^T  (WT is [Nout][K] bf16, pre-transposed)
// BM=128, BN=128, BK=128, 512 threads = 8 waves, wave w owns rows w*16..+15.
// LDS: XOR-swizzled 16B chunks (chunk ^ (row&7)), no padding, 64 KB total.
// MODE 0: bf16 out. MODE 2: silu->bf16. MODE 3: +resid -> f32 out.
// ---------------------------------------------------------------------------
template <int MODE, bool AF32>
__global__ __launch_bounds__(512) void gemm2_k(
    const void* __restrict__ Av, const bf16* __restrict__ WT,
    const float* __restrict__ bias, void* __restrict__ Cout,
    const float* __restrict__ resid, int M, int K, int Nout)
{
    __shared__ __bf16 As[128 * 128];
    __shared__ __bf16 Ws[128 * 128];

    const int tid  = threadIdx.x;
    const int wave = tid >> 6;
    const int lane = tid & 63;
    const int row0 = blockIdx.x * 128;
    const int col0 = blockIdx.y * 128;

    f32x4 acc[8];
#pragma unroll
    for (int i = 0; i < 8; i++) acc[i] = (f32x4){0.f, 0.f, 0.f, 0.f};

    for (int k0 = 0; k0 < K; k0 += 128) {
        // ---- stage A tile (128 x 128) ----
        if constexpr (AF32) {
            const float* A = (const float*)Av;
#pragma unroll
            for (int i = 0; i < 8; i++) {              // 4096 f32x4 chunks (8B bf16 out)
                int idx = tid + i * 512;
                int r = idx >> 5, c4 = idx & 31;
                bf16x4 o;
                if (row0 + r < M) {
                    f32x4 v = *reinterpret_cast<const f32x4*>(A + (size_t)(row0 + r) * K + k0 + c4 * 4);
#pragma unroll
                    for (int j = 0; j < 4; j++) o[j] = (__bf16)v[j];
                } else {
#pragma unroll
                    for (int j = 0; j < 4; j++) o[j] = (__bf16)0.f;
                }
                int col = (c4 >> 1) ^ (r & 7);
                *reinterpret_cast<bf16x4*>(&As[r * 128 + col * 8 + (c4 & 1) * 4]) = o;
            }
        } else {
            const bf16* A = (const bf16*)Av;
#pragma unroll
            for (int i = 0; i < 4; i++) {              // 2048 bf16x8 chunks
                int idx = tid + i * 512;
                int r = idx >> 4, c = idx & 15;
                bf16x8 v;
                if (row0 + r < M) {
                    v = *reinterpret_cast<const bf16x8*>(A + (size_t)(row0 + r) * K + k0 + c * 8);
                } else {
#pragma unroll
                    for (int j = 0; j < 8; j++) v[j] = (__bf16)0.f;
                }
                *reinterpret_cast<bf16x8*>(&As[r * 128 + ((c ^ (r & 7)) * 8)]) = v;
            }
        }
        // ---- stage W tile: WT rows col0..col0+127, k slice ----
#pragma unroll
        for (int i = 0; i < 4; i++) {
            int idx = tid + i * 512;
            int r = idx >> 4, c = idx & 15;
            bf16x8 v = *reinterpret_cast<const bf16x8*>(WT + (size_t)(col0 + r) * K + k0 + c * 8);
            *reinterpret_cast<bf16x8*>(&Ws[r * 128 + ((c ^ (r & 7)) * 8)]) = v;
        }
        __syncthreads();

        const int mrow = wave * 16 + (lane & 15);
        const int kq = lane >> 4;                       // 0..3
#pragma unroll
        for (int kk = 0; kk < 4; kk++) {                // K-steps of 32
            int cidx = kk * 4 + kq;                     // 16B chunk index (pre-swizzle)
            bf16x8 a = *reinterpret_cast<const bf16x8*>(&As[mrow * 128 + ((cidx ^ (mrow & 7)) * 8)]);
#pragma unroll
            for (int ct = 0; ct < 8; ct++) {
                int nrow = ct * 16 + (lane & 15);
                bf16x8 b = *reinterpret_cast<const bf16x8*>(&Ws[nrow * 128 + ((cidx ^ (nrow & 7)) * 8)]);
                acc[ct] = __builtin_amdgcn_mfma_f32_16x16x32_bf16(a, b, acc[ct], 0, 0, 0);
            }
        }
        __syncthreads();
    }

    // epilogue: C/D layout col=lane&15, row=(lane>>4)*4+reg
    const int rbase = row0 + wave * 16 + ((lane >> 4) << 2);
#pragma unroll
    for (int ct = 0; ct < 8; ct++) {
        int col = col0 + ct * 16 + (lane & 15);
        float bv = bias ? bias[col] : 0.f;
#pragma unroll
        for (int r = 0; r < 4; r++) {
            int row = rbase + r;
            if (row >= M) continue;
            float v = acc[ct][r] + bv;
            if constexpr (MODE == 2) v = v / (1.f + __expf(-v));
            if constexpr (MODE == 3) v += resid[(size_t)row * 128 + col];
            if constexpr (MODE == 3) {
                ((float*)Cout)[(size_t)row * Nout + col] = v;
            } else {
                ((bf16*)Cout)[(size_t)row * Nout + col] = __float2bfloat16(v);
            }
        }
    }
}

// ---------------------------------------------------------------------------
// LayerNorm: one wave per row (D=128, 2 channels/lane). f32 in -> bf16 out.
// ---------------------------------------------------------------------------
__global__ __launch_bounds__(256) void ln_k(
    const float* __restrict__ x, const float* __restrict__ g,
    const float* __restrict__ beta, bf16* __restrict__ h, int Nrows)
{
    int row = blockIdx.x * 4 + (threadIdx.x >> 6);
    int lane = threadIdx.x & 63;
    if (row >= Nrows) return;
    size_t base = (size_t)row * 128;
    float v0 = x[base + lane], v1 = x[base + lane + 64];
    float s = v0 + v1, ss = v0 * v0 + v1 * v1;
#pragma unroll
    for (int off = 32; off; off >>= 1) {
        s += __shfl_xor(s, off, 64);
        ss += __shfl_xor(ss, off, 64);
    }
    float mu = s * (1.f / 128.f);
    float var = ss * (1.f / 128.f) - mu * mu;
    float rs = rsqrtf(var + 1e-5f);
    h[base + lane]      = __float2bfloat16((v0 - mu) * rs * g[lane] + beta[lane]);
    h[base + lane + 64] = __float2bfloat16((v1 - mu) * rs * g[lane + 64] + beta[lane + 64]);
}

// ---------------------------------------------------------------------------
// CSR build
// ---------------------------------------------------------------------------
__global__ __launch_bounds__(256) void hist_k(const int* __restrict__ ei, int* __restrict__ cnt, int E)
{
    int e = blockIdx.x * 256 + threadIdx.x;
    if (e < E) atomicAdd(&cnt[ei[E + e]], 1);
}

__global__ __launch_bounds__(1024) void scan_k(const int* __restrict__ cnt, int* __restrict__ offset, int N)
{
    __shared__ int tmp[1024];
    __shared__ int s_running;
    int tid = threadIdx.x;
    if (tid == 0) { s_running = 0; offset[0] = 0; }
    __syncthreads();
    for (int base = 0; base < N; base += 1024) {
        int v = (base + tid < N) ? cnt[base + tid] : 0;
        tmp[tid] = v;
        __syncthreads();
#pragma unroll
        for (int off = 1; off < 1024; off <<= 1) {
            int t = (tid >= off) ? tmp[tid - off] : 0;
            __syncthreads();
            tmp[tid] += t;
            __syncthreads();
        }
        int run = s_running;
        if (base + tid < N) offset[base + tid + 1] = run + tmp[tid];
        __syncthreads();
        if (tid == 0) s_running = run + tmp[1023];
        __syncthreads();
    }
}

__global__ __launch_bounds__(256) void scatter_k(
    const int* __restrict__ ei, const int* __restrict__ offset,
    int* __restrict__ cursor, int2* __restrict__ sorted, int E)
{
    int e = blockIdx.x * 256 + threadIdx.x;
    if (e >= E) return;
    int src = ei[e];
    int dst = ei[E + e];
    int r = atomicAdd(&cursor[dst], 1);
    sorted[offset[dst] + r] = make_int2(src, e);
}

// ---------------------------------------------------------------------------
// Fused gather: one wave per dst node; QKVS layout [N][512] = Q|K|V|S (bf16).
// p = exp(q.(k+e)/4); register accumulation; then norm+skip+resid+LN2.
// Lane l holds channels 2l,2l+1; head = l>>3.
// ---------------------------------------------------------------------------
__global__ __launch_bounds__(256) void gather_k(
    const int2* __restrict__ sorted, const int* __restrict__ offset,
    const bf16* __restrict__ QKVS, const bf16* __restrict__ Ep,
    const float* __restrict__ x, const float* __restrict__ alpha,
    const float* __restrict__ g, const float* __restrict__ beta,
    float* __restrict__ xn, bf16* __restrict__ h2, int N)
{
    int node = blockIdx.x * 4 + (threadIdx.x >> 6);
    if (node >= N) return;
    int lane = threadIdx.x & 63;
    int c = lane * 2;

    bf16x2 qv = *reinterpret_cast<const bf16x2*>(QKVS + (size_t)node * 512 + c);
    float q0 = (float)qv[0], q1 = (float)qv[1];

    int start = offset[node], end = offset[node + 1];
    float den = 0.f, num0 = 0.f, num1 = 0.f;

    int2 se = (start < end) ? sorted[start] : make_int2(0, 0);
    for (int j = start; j < end; j++) {
        int2 cur = se;
        if (j + 1 < end) se = sorted[j + 1];
        const bf16* sp = QKVS + (size_t)cur.x * 512 + c;
        bf16x2 kv = *reinterpret_cast<const bf16x2*>(sp + 128);
        bf16x2 vv = *reinterpret_cast<const bf16x2*>(sp + 256);
        bf16x2 ev = *reinterpret_cast<const bf16x2*>(Ep + (size_t)cur.y * 128 + c);
        float e0 = (float)ev[0], e1 = (float)ev[1];
        float part = q0 * ((float)kv[0] + e0) + q1 * ((float)kv[1] + e1);
        part += __shfl_xor(part, 1, 64);
        part += __shfl_xor(part, 2, 64);
        part += __shfl_xor(part, 4, 64);
        float p = __expf(part * 0.25f);
        den  += p;
        num0 += p * ((float)vv[0] + e0);
        num1 += p * ((float)vv[1] + e1);
    }

    size_t base = (size_t)node * 128;
    float invz = 1.f / (den + 1e-16f);
    float al = alpha[0];
    float s0 = (float)QKVS[(size_t)node * 512 + 384 + c];
    float s1 = (float)QKVS[(size_t)node * 512 + 384 + c + 1];
    float o0 = num0 * invz + s0;
    float o1 = num1 * invz + s1;
    float x0 = x[base + c] + al * o0;
    float x1 = x[base + c + 1] + al * o1;
    xn[base + c] = x0;
    xn[base + c + 1] = x1;

    float s = x0 + x1, ss = x0 * x0 + x1 * x1;
#pragma unroll
    for (int off = 32; off; off >>= 1) {
        s += __shfl_xor(s, off, 64);
        ss += __shfl_xor(ss, off, 64);
    }
    float mu = s * (1.f / 128.f);
    float var = ss * (1.f / 128.f) - mu * mu;
    float rs = rsqrtf(var + 1e-5f);
    h2[base + c]     = __float2bfloat16((x0 - mu) * rs * g[c] + beta[c]);
    h2[base + c + 1] = __float2bfloat16((x1 - mu) * rs * g[c + 1] + beta[c + 1]);
}

// ---------------------------------------------------------------------------
extern "C" void kernel_launch(void* const* d_in, const int* in_sizes, int n_in,
                              void* d_out, int out_size, void* d_ws, size_t ws_size,
                              hipStream_t stream)
{
    const float* x         = (const float*)d_in[0];
    const float* edge_attr = (const float*)d_in[1];
    const int*   ei        = (const int*)d_in[2];
    const float* Wq = (const float*)d_in[3];  const float* bq = (const float*)d_in[4];
    const float* Wk = (const float*)d_in[5];  const float* bk = (const float*)d_in[6];
    const float* Wv = (const float*)d_in[7];  const float* bv = (const float*)d_in[8];
    const float* We = (const float*)d_in[9];
    const float* Wskip = (const float*)d_in[10]; const float* bskip = (const float*)d_in[11];
    const float* W1 = (const float*)d_in[12]; const float* b1 = (const float*)d_in[13];
    const float* W2 = (const float*)d_in[14]; const float* b2 = (const float*)d_in[15];
    const float* g1 = (const float*)d_in[16]; const float* beta1 = (const float*)d_in[17];
    const float* g2 = (const float*)d_in[18]; const float* beta2 = (const float*)d_in[19];
    const float* alpha = (const float*)d_in[20];

    const int N = in_sizes[0] / 128;
    const int E = in_sizes[2] / 2;

    char* w = (char*)d_ws;
    auto alloc = [&](size_t bytes) {
        char* p = w;
        w += (bytes + 255) & ~(size_t)255;
        return p;
    };
    bf16*  h      = (bf16*)alloc((size_t)N * 128 * 2);
    bf16*  QKVS   = (bf16*)alloc((size_t)N * 512 * 2);
    bf16*  Ep     = (bf16*)alloc((size_t)E * 128 * 2);
    float* xn     = (float*)alloc((size_t)N * 128 * 4);
    bf16*  h2     = (bf16*)alloc((size_t)N * 128 * 2);
    bf16*  t      = (bf16*)alloc((size_t)N * 512 * 2);
    int*   cnt    = (int*)alloc((size_t)N * 4);
    int*   cursor = (int*)alloc((size_t)N * 4);
    int*   offset = (int*)alloc((size_t)(N + 1) * 4);
    int2*  sorted = (int2*)alloc((size_t)E * 8);
    bf16*  WTqkvs = (bf16*)alloc((size_t)512 * 128 * 2);
    bf16*  WTe    = (bf16*)alloc((size_t)128 * 128 * 2);
    bf16*  WT1    = (bf16*)alloc((size_t)512 * 128 * 2);
    bf16*  WT2    = (bf16*)alloc((size_t)128 * 512 * 2);
    float* bqkvs  = (float*)alloc((size_t)512 * 4);

    // weight prep (tiny)
    t_k<<<64, 256, 0, stream>>>(Wq, WTqkvs, 128, 128);
    t_k<<<64, 256, 0, stream>>>(Wk, WTqkvs + 128 * 128, 128, 128);
    t_k<<<64, 256, 0, stream>>>(Wv, WTqkvs + 256 * 128, 128, 128);
    t_k<<<64, 256, 0, stream>>>(Wskip, WTqkvs + 384 * 128, 128, 128);
    t_k<<<64, 256, 0, stream>>>(We, WTe, 128, 128);
    t_k<<<256, 256, 0, stream>>>(W1, WT1, 128, 512);
    t_k<<<256, 256, 0, stream>>>(W2, WT2, 512, 128);
    bcat_k<<<2, 256, 0, stream>>>(bq, bk, bv, bskip, bqkvs);

    // CSR build
    hipMemsetAsync(cnt, 0, (size_t)N * 4, stream);
    hipMemsetAsync(cursor, 0, (size_t)N * 4, stream);
    hist_k<<<(E + 255) / 256, 256, 0, stream>>>(ei, cnt, E);
    scan_k<<<1, 1024, 0, stream>>>(cnt, offset, N);
    scatter_k<<<(E + 255) / 256, 256, 0, stream>>>(ei, offset, cursor, sorted, E);

    // LN1
    ln_k<<<(N + 3) / 4, 256, 0, stream>>>(x, g1, beta1, h, N);

    // fused Q|K|V|S GEMM -> QKVS [N][512]
    gemm2_k<0, false><<<dim3((N + 127) / 128, 4), 512, 0, stream>>>(h, WTqkvs, bqkvs, QKVS, nullptr, N, 128, 512);

    // edge projection: Ep = edge_attr(f32) @ We -> bf16
    gemm2_k<0, true><<<dim3((E + 127) / 128, 1), 512, 0, stream>>>(edge_attr, WTe, nullptr, Ep, nullptr, E, 128, 128);

    // fused gather: attention + normalize + skip + residual + LN2
    gather_k<<<(N + 3) / 4, 256, 0, stream>>>(sorted, offset, QKVS, Ep, x, alpha, g2, beta2, xn, h2, N);

    // FFN
    gemm2_k<2, false><<<dim3((N + 127) / 128, 4), 512, 0, stream>>>(h2, WT1, b1, t, nullptr, N, 128, 512);
    gemm2_k<3, false><<<dim3((N + 127) / 128, 1), 512, 0, stream>>>(t, WT2, b2, d_out, xn, N, 512, 128);
}